// Round 1
// baseline (4530.072 us; speedup 1.0000x reference)
//
#include <hip/hip_runtime.h>
#include <math.h>

#define T_STEPS 512
#define BATCH   64
#define DIM     1024
#define NB      16
#define NS      64
#define TOK     (T_STEPS*BATCH)   // 32768
#define CH      64                // time-steps per chunk
#define NCHUNK  (T_STEPS/CH)      // 8

// ---- workspace layout (float offsets) ----
#define WS_LOGITS 0                                   // TOK*16
#define WS_Q      (WS_LOGITS + TOK*NB)                // TOK*64
#define WS_S      (WS_Q + TOK*NS)                     // 1024*64*64 carried state
#define WS_KV     (WS_S + BATCH*NB*NS*NS)             // CH*BATCH*2048
#define WS_BETA   (WS_KV + CH*BATCH*2*NS*NB)          // CH*BATCH*1024
// total = 19,398,656 floats ~= 78 MB

// ---------------- router logits, fp64 accumulate (top-k robustness) ----------
__global__ __launch_bounds__(256) void logits_kernel(
    const float* __restrict__ x, const float* __restrict__ Wr,
    float* __restrict__ logits)
{
  __shared__ __align__(16) float xsh[16][132];  // +4 pad breaks 4-way bank alias
  __shared__ __align__(16) float wsh[16][132];
  const int tid  = threadIdx.x;
  const int tloc = tid >> 4, cc = tid & 15;
  const int tok0 = blockIdx.x << 4;
  double acc = 0.0;
  for (int k0 = 0; k0 < DIM; k0 += 128) {
    #pragma unroll
    for (int e = 0; e < 2; e++) {
      int f = tid + (e << 8);            // 512 float4s: 16 rows x 32
      int r = f >> 5, c4 = (f & 31) << 2;
      *(float4*)&xsh[r][c4] = *(const float4*)&x[(size_t)(tok0 + r)*DIM + k0 + c4];
      *(float4*)&wsh[r][c4] = *(const float4*)&Wr[(size_t)r*DIM + k0 + c4];
    }
    __syncthreads();
    #pragma unroll 8
    for (int kk = 0; kk < 128; kk++)
      acc += (double)xsh[tloc][kk] * (double)wsh[cc][kk];
    __syncthreads();
  }
  logits[(size_t)(tok0 + tloc)*NB + cc] = (float)acc;
}

// ---------------- generic fp32 SGEMM: C[M,N] = A[M,K] * B[N,K]^T -------------
// M,N multiples of 64; K multiple of 16. grid=(M/64, N/64), 256 threads.
__global__ __launch_bounds__(256) void sgemm_kernel(
    const float* __restrict__ A, const float* __restrict__ B,
    float* __restrict__ C, int N, int K)
{
  __shared__ __align__(16) float As[16][64];   // [k][m]
  __shared__ __align__(16) float Bs[16][64];   // [k][n]
  const int tid = threadIdx.x;
  const int tx = tid & 15, ty = tid >> 4;
  const int m0 = blockIdx.x << 6, n0 = blockIdx.y << 6;
  const int lr = tid >> 2, lk = (tid & 3) << 2;
  float acc[4][4] = {{0.f,0.f,0.f,0.f},{0.f,0.f,0.f,0.f},
                     {0.f,0.f,0.f,0.f},{0.f,0.f,0.f,0.f}};
  for (int k0 = 0; k0 < K; k0 += 16) {
    float4 a = *(const float4*)&A[(size_t)(m0+lr)*K + k0 + lk];
    float4 b = *(const float4*)&B[(size_t)(n0+lr)*K + k0 + lk];
    As[lk+0][lr]=a.x; As[lk+1][lr]=a.y; As[lk+2][lr]=a.z; As[lk+3][lr]=a.w;
    Bs[lk+0][lr]=b.x; Bs[lk+1][lr]=b.y; Bs[lk+2][lr]=b.z; Bs[lk+3][lr]=b.w;
    __syncthreads();
    #pragma unroll
    for (int kk = 0; kk < 16; kk++) {
      float4 av = *(const float4*)&As[kk][ty<<2];
      float4 bv = *(const float4*)&Bs[kk][tx<<2];
      acc[0][0] += av.x*bv.x; acc[0][1] += av.x*bv.y; acc[0][2] += av.x*bv.z; acc[0][3] += av.x*bv.w;
      acc[1][0] += av.y*bv.x; acc[1][1] += av.y*bv.y; acc[1][2] += av.y*bv.z; acc[1][3] += av.y*bv.w;
      acc[2][0] += av.z*bv.x; acc[2][1] += av.z*bv.y; acc[2][2] += av.z*bv.z; acc[2][3] += av.z*bv.w;
      acc[3][0] += av.w*bv.x; acc[3][1] += av.w*bv.y; acc[3][2] += av.w*bv.z; acc[3][3] += av.w*bv.w;
    }
    __syncthreads();
  }
  #pragma unroll
  for (int u = 0; u < 4; u++)
    *(float4*)&C[(size_t)(m0 + (ty<<2) + u)*N + n0 + (tx<<2)] =
        make_float4(acc[u][0], acc[u][1], acc[u][2], acc[u][3]);
}

// ---------------- recurrence: one wave per (batch, block) --------------------
__device__ __forceinline__ float fast_tanh(float v) {
  v = fminf(15.f, fmaxf(-15.f, v));
  float e = __expf(2.f*v);
  return (e - 1.f) * __builtin_amdgcn_rcpf(e + 1.f);
}

__global__ __launch_bounds__(256) void recur_kernel(
    const float* __restrict__ logits,  // [TOK][16] (global t index)
    const float* __restrict__ kv,      // chunk: [CH*BATCH][2048]
    const float* __restrict__ betap,   // chunk: [CH*BATCH][1024]
    const float* __restrict__ qb,      // [TOK][64] (global t index)
    const float* __restrict__ b_beta,  // [16][64]
    float* __restrict__ out,           // [TOK][64], pre-zeroed, atomic accum
    float* __restrict__ Sfin,          // [B][16][64][64] (d_out tail)
    float* __restrict__ Sws,           // [1024][64][64] carried state
    int t0, int first, int last)
{
  const int wv   = threadIdx.x >> 6;
  const int lane = threadIdx.x & 63;
  const int task = blockIdx.x * 4 + wv;      // 0..1023
  const int b = task >> 4, c = task & 15;
  __shared__ __align__(16) float sh[4][128]; // per-wave: [0:64)=k_norm, [64:128)=q

  float S[NS];
  float* Sp = Sws + ((size_t)task*NS + lane)*NS;
  if (first) {
    #pragma unroll
    for (int j = 0; j < NS; j++) S[j] = 0.f;
  } else {
    #pragma unroll
    for (int j = 0; j < NS; j += 4) {
      float4 v = *(const float4*)&Sp[j];
      S[j]=v.x; S[j+1]=v.y; S[j+2]=v.z; S[j+3]=v.w;
    }
  }
  const float bb = b_beta[c*NS + lane];

  #pragma unroll 1
  for (int t = t0; t < t0 + CH; t++) {
    const int tok  = t*BATCH + b;
    const int tloc = (t - t0)*BATCH + b;
    const float* lg = logits + (size_t)tok*NB;
    float lv[NB];
    #pragma unroll
    for (int l = 0; l < NB; l++) lv[l] = lg[l];
    // top-2 (strict > keeps lowest index on ties, matching lax.top_k)
    float v1 = lv[0]; int m1 = 0;
    #pragma unroll
    for (int l = 1; l < NB; l++) if (lv[l] > v1) { v1 = lv[l]; m1 = l; }
    float v2 = -3.4e38f; int m2 = 0;
    #pragma unroll
    for (int l = 0; l < NB; l++) if (l != m1 && lv[l] > v2) { v2 = lv[l]; m2 = l; }
    // softmax weight for this block (avoid dynamic reg indexing)
    float sum = 0.f, num = 0.f;
    #pragma unroll
    for (int l = 0; l < NB; l++) {
      float e = __expf(lv[l] - v1);
      sum += e;
      if (l == c) num = e;
    }
    const float wc = num * __builtin_amdgcn_rcpf(sum);

    if (c == m1 || c == m2) {                    // wave-uniform branch
      const float* kvp = kv + (size_t)tloc*(2*NS*NB) + c*(2*NS);
      const float ki = kvp[lane];
      const float vi = kvp[NS + lane];
      const float bp = betap[(size_t)tloc*(NS*NB) + c*NS + lane] + bb;
      const float beta = __builtin_amdgcn_rcpf(1.f + __expf(-bp));
      float s2 = ki*ki;
      #pragma unroll
      for (int off = 32; off; off >>= 1) s2 += __shfl_xor(s2, off);
      const float kn_i = ki * __builtin_amdgcn_rcpf(sqrtf(s2) + 1e-6f);
      sh[wv][lane] = kn_i;                       // wave-lockstep LDS broadcast
      __builtin_amdgcn_wave_barrier();
      float r = 0.f;
      #pragma unroll
      for (int j = 0; j < NS; j += 4) {
        float4 k4 = *(const float4*)&sh[wv][j];
        r += S[j]*k4.x + S[j+1]*k4.y + S[j+2]*k4.z + S[j+3]*k4.w;
      }
      const float delta = vi - r;
      #pragma unroll
      for (int j = 0; j < NS; j += 4) {
        float4 k4 = *(const float4*)&sh[wv][j];
        S[j+0] = fast_tanh(beta*S[j+0] + delta*k4.x);
        S[j+1] = fast_tanh(beta*S[j+1] + delta*k4.y);
        S[j+2] = fast_tanh(beta*S[j+2] + delta*k4.z);
        S[j+3] = fast_tanh(beta*S[j+3] + delta*k4.w);
      }
    }
    // Sq + gated output, every block every step
    sh[wv][NS + lane] = qb[(size_t)tok*NS + lane];
    __builtin_amdgcn_wave_barrier();
    float sq = 0.f;
    #pragma unroll
    for (int j = 0; j < NS; j += 4) {
      float4 q4 = *(const float4*)&sh[wv][NS + j];
      sq += S[j]*q4.x + S[j+1]*q4.y + S[j+2]*q4.z + S[j+3]*q4.w;
    }
    const float bo = sq*sq * __builtin_amdgcn_rcpf(1.f + __expf(-sq)); // Sq*silu(Sq)
    unsafeAtomicAdd(&out[(size_t)tok*NS + lane], wc*bo);
  }

  #pragma unroll
  for (int j = 0; j < NS; j += 4)
    *(float4*)&Sp[j] = make_float4(S[j], S[j+1], S[j+2], S[j+3]);
  if (last) {
    float* dst = Sfin + (((size_t)b*NB + c)*NS + lane)*NS;
    #pragma unroll
    for (int j = 0; j < NS; j += 4)
      *(float4*)&dst[j] = make_float4(S[j], S[j+1], S[j+2], S[j+3]);
  }
}

extern "C" void kernel_launch(void* const* d_in, const int* in_sizes, int n_in,
                              void* d_out, int out_size, void* d_ws, size_t ws_size,
                              hipStream_t stream) {
  const float* x        = (const float*)d_in[0];
  const float* W_router = (const float*)d_in[1];
  const float* W_kv     = (const float*)d_in[2];
  const float* W_beta   = (const float*)d_in[3];
  const float* b_beta   = (const float*)d_in[4];
  const float* W_q      = (const float*)d_in[5];

  float* out  = (float*)d_out;
  float* Sfin = out + (size_t)TOK*NS;          // S_final region of d_out
  float* ws     = (float*)d_ws;
  float* logits = ws + WS_LOGITS;
  float* qb     = ws + WS_Q;
  float* Sws    = ws + WS_S;
  float* kvc    = ws + WS_KV;
  float* bpc    = ws + WS_BETA;

  // outputs region is accumulated with atomics -> zero it (d_out is poisoned)
  hipMemsetAsync(out, 0, (size_t)TOK*NS*sizeof(float), stream);

  logits_kernel<<<TOK/16, 256, 0, stream>>>(x, W_router, logits);
  sgemm_kernel<<<dim3(TOK/64, NS/64), 256, 0, stream>>>(x, W_q, qb, NS, DIM);

  for (int ci = 0; ci < NCHUNK; ci++) {
    const float* xc = x + (size_t)ci*CH*BATCH*DIM;
    sgemm_kernel<<<dim3(CH*BATCH/64, (2*NS*NB)/64), 256, 0, stream>>>(
        xc, W_kv, kvc, 2*NS*NB, DIM);
    sgemm_kernel<<<dim3(CH*BATCH/64, (NS*NB)/64), 256, 0, stream>>>(
        xc, W_beta, bpc, NS*NB, DIM);
    recur_kernel<<<(BATCH*NB)/4, 256, 0, stream>>>(
        logits, kvc, bpc, qb, b_beta, out, Sfin, Sws,
        ci*CH, ci == 0 ? 1 : 0, ci == NCHUNK-1 ? 1 : 0);
  }
}

// Round 2
// 1352.337 us; speedup vs baseline: 3.3498x; 3.3498x over previous
//
#include <hip/hip_runtime.h>
#include <math.h>

#define T_STEPS 512
#define BATCH   64
#define DIM     1024
#define NB      16
#define NS      64
#define TOK     (T_STEPS*BATCH)        // 32768
#define SELROWS (2*TOK + NB*64)        // 66560 (spare rows for tile padding)
#define MAXTILES ((2*TOK)/64 + NB)     // 1040

// ---- workspace layout (float offsets) ----
#define WS_LOGITS 0                        // TOK*16
#define WS_W      (WS_LOGITS + TOK*NB)     // TOK*16 softmax weights
#define WS_Q      (WS_W + TOK*NB)          // TOK*64
#define WS_SEL    (WS_Q + TOK*NS)          // TOK ints (m1|m2<<8)
#define WS_TOKL   (WS_SEL + TOK)           // NB*TOK ints (per-block token lists)
#define WS_SELL   (WS_TOKL + NB*TOK)       // NB*TOK ints (per-block scatter rows)
#define WS_CNT    (WS_SELL + NB*TOK)       // 16 ints
#define WS_TILE   (WS_CNT + 16)            // 32 ints (tile prefix, [16]=total)
#define WS_KVSEL  (WS_TILE + 32)           // SELROWS*192 floats (k|v|beta+bias)
// total ~ 17.0M floats = 68 MB

// ---------------- router logits, fp64 accumulate (top-k robustness) ----------
__global__ __launch_bounds__(256) void logits_kernel(
    const float* __restrict__ x, const float* __restrict__ Wr,
    float* __restrict__ logits)
{
  __shared__ __align__(16) float xsh[16][132];
  __shared__ __align__(16) float wsh[16][132];
  const int tid  = threadIdx.x;
  const int tloc = tid >> 4, cc = tid & 15;
  const int tok0 = blockIdx.x << 4;
  double acc = 0.0;
  for (int k0 = 0; k0 < DIM; k0 += 128) {
    #pragma unroll
    for (int e = 0; e < 2; e++) {
      int f = tid + (e << 8);
      int r = f >> 5, c4 = (f & 31) << 2;
      *(float4*)&xsh[r][c4] = *(const float4*)&x[(size_t)(tok0 + r)*DIM + k0 + c4];
      *(float4*)&wsh[r][c4] = *(const float4*)&Wr[(size_t)r*DIM + k0 + c4];
    }
    __syncthreads();
    #pragma unroll 8
    for (int kk = 0; kk < 128; kk++)
      acc += (double)xsh[tloc][kk] * (double)wsh[cc][kk];
    __syncthreads();
  }
  logits[(size_t)(tok0 + tloc)*NB + cc] = (float)acc;
}

// ---------------- routing: top-2, softmax weights, bucket by block ----------
__global__ __launch_bounds__(256) void route_kernel(
    const float* __restrict__ logits, float* __restrict__ w,
    int* __restrict__ selp, int* __restrict__ toklist,
    int* __restrict__ sellist, int* __restrict__ cnt)
{
  const int tok = blockIdx.x*256 + threadIdx.x;
  const float* lg = logits + (size_t)tok*NB;
  float lv[NB];
  #pragma unroll
  for (int l = 0; l < NB; l++) lv[l] = lg[l];
  float v1 = lv[0]; int m1 = 0;
  #pragma unroll
  for (int l = 1; l < NB; l++) if (lv[l] > v1) { v1 = lv[l]; m1 = l; }
  float v2 = -3.4e38f; int m2 = 0;
  #pragma unroll
  for (int l = 0; l < NB; l++) if (l != m1 && lv[l] > v2) { v2 = lv[l]; m2 = l; }
  float ev[NB], sum = 0.f;
  #pragma unroll
  for (int l = 0; l < NB; l++) { ev[l] = __expf(lv[l] - v1); sum += ev[l]; }
  const float rs = __builtin_amdgcn_rcpf(sum);
  #pragma unroll
  for (int l = 0; l < NB; l++) w[(size_t)tok*NB + l] = ev[l] * rs;
  selp[tok] = m1 | (m2 << 8);
  int p1 = atomicAdd(&cnt[m1], 1);
  toklist[m1*TOK + p1] = tok;  sellist[m1*TOK + p1] = 2*tok;
  int p2 = atomicAdd(&cnt[m2], 1);
  toklist[m2*TOK + p2] = tok;  sellist[m2*TOK + p2] = 2*tok + 1;
}

// ---------------- tile prefix + pad tail tiles --------------------------------
__global__ void prefix_kernel(const int* __restrict__ cnt, int* __restrict__ tile,
                              int* __restrict__ toklist, int* __restrict__ sellist)
{
  __shared__ int off[NB+1];
  if (threadIdx.x == 0) {
    int a = 0;
    for (int c = 0; c < NB; c++) { off[c] = a; tile[c] = a; a += (cnt[c] + 63) >> 6; }
    off[NB] = a; tile[NB] = a;
  }
  __syncthreads();
  for (int c = 0; c < NB; c++) {
    const int s = cnt[c], e = (off[c+1] - off[c]) << 6;
    for (int i = s + threadIdx.x; i < e; i += 256) {
      toklist[c*TOK + i] = 0;                        // dummy A row
      sellist[c*TOK + i] = 2*TOK + c*64 + (i & 63);  // spare scatter slot
    }
  }
}

// ---------------- gather-GEMM over selections ---------------------------------
// C[sel][192] = x[tok] * [W_kv(c) rows | W_beta(c) rows]^T (+ b_beta on y==2)
__global__ __launch_bounds__(256) void gather_gemm_kernel(
    const float* __restrict__ x, const float* __restrict__ W_kv,
    const float* __restrict__ W_beta, const float* __restrict__ b_beta,
    const int* __restrict__ tileoff, const int* __restrict__ toklist,
    const int* __restrict__ sellist, float* __restrict__ kvsel)
{
  __shared__ __align__(16) float As[16][68];   // [k][m], +4 pad: 2-way writes
  __shared__ __align__(16) float Bs[16][68];
  __shared__ int tl[64], sl[64];
  const int tile = blockIdx.x;
  if (tile >= tileoff[NB]) return;
  int c = 0;
  while (c < NB-1 && tile >= tileoff[c+1]) c++;
  const int ti = tile - tileoff[c];
  const int tid = threadIdx.x;
  if (tid < 64) {
    tl[tid] = toklist[c*TOK + (ti<<6) + tid];
    sl[tid] = sellist[c*TOK + (ti<<6) + tid];
  }
  __syncthreads();
  const int y = blockIdx.y;
  const float* Bp = (y < 2) ? (W_kv + ((size_t)c*128 + y*64)*DIM)
                            : (W_beta + (size_t)c*64*DIM);
  const int tx = tid & 15, ty = tid >> 4;
  const int lr = tid >> 2, lk = (tid & 3) << 2;
  const float* Ap = x + (size_t)tl[lr]*DIM;
  float acc[4][4] = {{0.f,0.f,0.f,0.f},{0.f,0.f,0.f,0.f},
                     {0.f,0.f,0.f,0.f},{0.f,0.f,0.f,0.f}};
  for (int k0 = 0; k0 < DIM; k0 += 16) {
    float4 a = *(const float4*)&Ap[k0 + lk];
    float4 b = *(const float4*)&Bp[(size_t)lr*DIM + k0 + lk];
    As[lk+0][lr]=a.x; As[lk+1][lr]=a.y; As[lk+2][lr]=a.z; As[lk+3][lr]=a.w;
    Bs[lk+0][lr]=b.x; Bs[lk+1][lr]=b.y; Bs[lk+2][lr]=b.z; Bs[lk+3][lr]=b.w;
    __syncthreads();
    #pragma unroll
    for (int kk = 0; kk < 16; kk++) {
      float4 av = *(const float4*)&As[kk][ty<<2];
      float4 bv = *(const float4*)&Bs[kk][tx<<2];
      acc[0][0] += av.x*bv.x; acc[0][1] += av.x*bv.y; acc[0][2] += av.x*bv.z; acc[0][3] += av.x*bv.w;
      acc[1][0] += av.y*bv.x; acc[1][1] += av.y*bv.y; acc[1][2] += av.y*bv.z; acc[1][3] += av.y*bv.w;
      acc[2][0] += av.z*bv.x; acc[2][1] += av.z*bv.y; acc[2][2] += av.z*bv.z; acc[2][3] += av.z*bv.w;
      acc[3][0] += av.w*bv.x; acc[3][1] += av.w*bv.y; acc[3][2] += av.w*bv.z; acc[3][3] += av.w*bv.w;
    }
    __syncthreads();
  }
  float4 bias = make_float4(0.f,0.f,0.f,0.f);
  if (y == 2) bias = *(const float4*)&b_beta[c*64 + (tx<<2)];
  #pragma unroll
  for (int u = 0; u < 4; u++) {
    const int srow = sl[(ty<<2) + u];
    *(float4*)&kvsel[(size_t)srow*192 + y*64 + (tx<<2)] =
        make_float4(acc[u][0]+bias.x, acc[u][1]+bias.y,
                    acc[u][2]+bias.z, acc[u][3]+bias.w);
  }
}

// ---------------- dense SGEMM for q: C[M,64] = A[M,K]*B[64,K]^T ---------------
__global__ __launch_bounds__(256) void sgemm_kernel(
    const float* __restrict__ A, const float* __restrict__ B,
    float* __restrict__ C, int N, int K)
{
  __shared__ __align__(16) float As[16][68];
  __shared__ __align__(16) float Bs[16][68];
  const int tid = threadIdx.x;
  const int tx = tid & 15, ty = tid >> 4;
  const int m0 = blockIdx.x << 6, n0 = blockIdx.y << 6;
  const int lr = tid >> 2, lk = (tid & 3) << 2;
  float acc[4][4] = {{0.f,0.f,0.f,0.f},{0.f,0.f,0.f,0.f},
                     {0.f,0.f,0.f,0.f},{0.f,0.f,0.f,0.f}};
  for (int k0 = 0; k0 < K; k0 += 16) {
    float4 a = *(const float4*)&A[(size_t)(m0+lr)*K + k0 + lk];
    float4 b = *(const float4*)&B[(size_t)(n0+lr)*K + k0 + lk];
    As[lk+0][lr]=a.x; As[lk+1][lr]=a.y; As[lk+2][lr]=a.z; As[lk+3][lr]=a.w;
    Bs[lk+0][lr]=b.x; Bs[lk+1][lr]=b.y; Bs[lk+2][lr]=b.z; Bs[lk+3][lr]=b.w;
    __syncthreads();
    #pragma unroll
    for (int kk = 0; kk < 16; kk++) {
      float4 av = *(const float4*)&As[kk][ty<<2];
      float4 bv = *(const float4*)&Bs[kk][tx<<2];
      acc[0][0] += av.x*bv.x; acc[0][1] += av.x*bv.y; acc[0][2] += av.x*bv.z; acc[0][3] += av.x*bv.w;
      acc[1][0] += av.y*bv.x; acc[1][1] += av.y*bv.y; acc[1][2] += av.y*bv.z; acc[1][3] += av.y*bv.w;
      acc[2][0] += av.z*bv.x; acc[2][1] += av.z*bv.y; acc[2][2] += av.z*bv.z; acc[2][3] += av.z*bv.w;
      acc[3][0] += av.w*bv.x; acc[3][1] += av.w*bv.y; acc[3][2] += av.w*bv.z; acc[3][3] += av.w*bv.w;
    }
    __syncthreads();
  }
  #pragma unroll
  for (int u = 0; u < 4; u++)
    *(float4*)&C[(size_t)(m0 + (ty<<2) + u)*N + n0 + (tx<<2)] =
        make_float4(acc[u][0], acc[u][1], acc[u][2], acc[u][3]);
}

// ---------------- recurrence: one wave per (batch, block), 512 steps ----------
__device__ __forceinline__ float fast_tanh(float v) {
  v = fminf(15.f, fmaxf(-15.f, v));
  float e = __expf(2.f*v);
  return (e - 1.f) * __builtin_amdgcn_rcpf(e + 1.f);
}

__global__ __launch_bounds__(256) void recur_kernel(
    const int* __restrict__ selp,     // [TOK] m1|m2<<8
    const float* __restrict__ w,      // [TOK][16]
    const float* __restrict__ kvsel,  // [SELROWS][192] k|v|beta_pre
    const float* __restrict__ qb,     // [TOK][64]
    float* __restrict__ out,          // [TOK][64] atomic accum (pre-zeroed)
    float* __restrict__ Sfin)         // [B][16][64][64]
{
  const int wv   = threadIdx.x >> 6;
  const int lane = threadIdx.x & 63;
  const int task = blockIdx.x * 4 + wv;
  const int b = task >> 4, c = task & 15;
  __shared__ __align__(16) float sh[4][128];  // [0:64)=k_norm, [64:128)=q

  float S[NS];
  #pragma unroll
  for (int j = 0; j < NS; j++) S[j] = 0.f;

  auto loadkv = [&](int meta, int t, float& k, float& v, float& bp) {
    const int m1 = meta & 0xFF, m2 = meta >> 8;
    if (c == m1 || c == m2) {                     // wave-uniform
      const size_t sidx = 2*(size_t)(t*BATCH + b) + (c == m2 ? 1 : 0);
      const float* row = kvsel + sidx*192;
      k = row[lane]; v = row[64 + lane]; bp = row[128 + lane];
    }
  };

  // pipeline preload: meta depth-3, data depth-2
  int   m_t  = selp[b], m_t1 = selp[BATCH + b], m_t2 = selp[2*BATCH + b];
  float wc_t = w[(size_t)b*NB + c], wc_t1 = w[(size_t)(BATCH + b)*NB + c];
  float q_t  = qb[(size_t)b*NS + lane], q_t1 = qb[(size_t)(BATCH + b)*NS + lane];
  float k_t=0.f, v_t=0.f, bp_t=0.f, k_t1=0.f, v_t1=0.f, bp_t1=0.f;
  loadkv(m_t, 0, k_t, v_t, bp_t);
  loadkv(m_t1, 1, k_t1, v_t1, bp_t1);

  #pragma unroll 1
  for (int t = 0; t < T_STEPS; t++) {
    const int tn  = (t+2 < T_STEPS) ? t+2 : T_STEPS-1;
    const int tn3 = (t+3 < T_STEPS) ? t+3 : T_STEPS-1;
    // issue prefetches first
    const int   m_t3  = selp[tn3*BATCH + b];
    const float wc_t2 = w[(size_t)(tn*BATCH + b)*NB + c];
    const float q_t2  = qb[(size_t)(tn*BATCH + b)*NS + lane];
    float k_t2=0.f, v_t2=0.f, bp_t2=0.f;
    loadkv(m_t2, tn, k_t2, v_t2, bp_t2);

    // ---- compute step t ----
    const int m1 = m_t & 0xFF, m2 = m_t >> 8;
    if (c == m1 || c == m2) {
      float s2 = k_t*k_t;
      #pragma unroll
      for (int off = 32; off; off >>= 1) s2 += __shfl_xor(s2, off);
      const float kn = k_t * __builtin_amdgcn_rcpf(sqrtf(s2) + 1e-6f);
      sh[wv][lane] = kn;
      __builtin_amdgcn_wave_barrier();
      const float beta = __builtin_amdgcn_rcpf(1.f + __expf(-bp_t));
      float r = 0.f;
      #pragma unroll
      for (int j = 0; j < NS; j += 4) {
        float4 k4 = *(const float4*)&sh[wv][j];
        r += S[j]*k4.x + S[j+1]*k4.y + S[j+2]*k4.z + S[j+3]*k4.w;
      }
      const float delta = v_t - r;
      #pragma unroll
      for (int j = 0; j < NS; j += 4) {
        float4 k4 = *(const float4*)&sh[wv][j];
        S[j+0] = fast_tanh(beta*S[j+0] + delta*k4.x);
        S[j+1] = fast_tanh(beta*S[j+1] + delta*k4.y);
        S[j+2] = fast_tanh(beta*S[j+2] + delta*k4.z);
        S[j+3] = fast_tanh(beta*S[j+3] + delta*k4.w);
      }
      __builtin_amdgcn_wave_barrier();
    }
    sh[wv][NS + lane] = q_t;
    __builtin_amdgcn_wave_barrier();
    float sq = 0.f;
    #pragma unroll
    for (int j = 0; j < NS; j += 4) {
      float4 q4 = *(const float4*)&sh[wv][NS + j];
      sq += S[j]*q4.x + S[j+1]*q4.y + S[j+2]*q4.z + S[j+3]*q4.w;
    }
    __builtin_amdgcn_wave_barrier();
    const float bo = sq*sq * __builtin_amdgcn_rcpf(1.f + __expf(-sq));
    unsafeAtomicAdd(&out[(size_t)(t*BATCH + b)*NS + lane], wc_t*bo);

    // rotate pipeline
    m_t = m_t1; m_t1 = m_t2; m_t2 = m_t3;
    wc_t = wc_t1; wc_t1 = wc_t2;
    q_t = q_t1;  q_t1 = q_t2;
    k_t = k_t1;  v_t = v_t1;  bp_t = bp_t1;
    k_t1 = k_t2; v_t1 = v_t2; bp_t1 = bp_t2;
  }

  float* dst = Sfin + (((size_t)b*NB + c)*NS + lane)*NS;
  #pragma unroll
  for (int j = 0; j < NS; j += 4)
    *(float4*)&dst[j] = make_float4(S[j], S[j+1], S[j+2], S[j+3]);
}

extern "C" void kernel_launch(void* const* d_in, const int* in_sizes, int n_in,
                              void* d_out, int out_size, void* d_ws, size_t ws_size,
                              hipStream_t stream) {
  const float* x        = (const float*)d_in[0];
  const float* W_router = (const float*)d_in[1];
  const float* W_kv     = (const float*)d_in[2];
  const float* W_beta   = (const float*)d_in[3];
  const float* b_beta   = (const float*)d_in[4];
  const float* W_q      = (const float*)d_in[5];

  float* out  = (float*)d_out;
  float* Sfin = out + (size_t)TOK*NS;
  float* ws     = (float*)d_ws;
  float* logits = ws + WS_LOGITS;
  float* wsm    = ws + WS_W;
  float* qb     = ws + WS_Q;
  int*   selp   = (int*)(ws + WS_SEL);
  int*   toklist= (int*)(ws + WS_TOKL);
  int*   sellist= (int*)(ws + WS_SELL);
  int*   cnt    = (int*)(ws + WS_CNT);
  int*   tile   = (int*)(ws + WS_TILE);
  float* kvsel  = ws + WS_KVSEL;

  hipMemsetAsync(out, 0, (size_t)TOK*NS*sizeof(float), stream);
  hipMemsetAsync(cnt, 0, 16*sizeof(int), stream);

  logits_kernel<<<TOK/16, 256, 0, stream>>>(x, W_router, logits);
  sgemm_kernel<<<dim3(TOK/64, 1), 256, 0, stream>>>(x, W_q, qb, NS, DIM);
  route_kernel<<<TOK/256, 256, 0, stream>>>(logits, wsm, selp, toklist, sellist, cnt);
  prefix_kernel<<<1, 256, 0, stream>>>(cnt, tile, toklist, sellist);
  gather_gemm_kernel<<<dim3(MAXTILES, 3), 256, 0, stream>>>(
      x, W_kv, W_beta, b_beta, tile, toklist, sellist, kvsel);
  recur_kernel<<<(BATCH*NB)/4, 256, 0, stream>>>(selp, wsm, kvsel, qb, out, Sfin);
}